// Round 12
// baseline (537.053 us; speedup 1.0000x reference)
//
#include <hip/hip_runtime.h>
#include <hip/hip_bf16.h>
#include <cstdint>
#include <cstddef>

// ---------------- problem constants ----------------
#define BB 512
#define SS 500
#define TT 499            // scan steps t = 0..498
#define NRB 256           // recurrence blocks (2 rows each)
#define L2E 1.4426950408889634f

typedef float  f32x4  __attribute__((ext_vector_type(4)));
typedef short  bf16x8 __attribute__((ext_vector_type(8)));

#define MFMA16(A, B, C) __builtin_amdgcn_mfma_f32_16x16x32_bf16((A), (B), (C), 0, 0, 0)

// ---------------- workspace layout (bytes) ----------------
// interleaved tables: element [row*128+col] = float2 { x-part, kip-part(-L2E-scaled) }
static constexpr size_t OFF_TQ    = 0;                 // 10000*128*8
static constexpr size_t OFF_TC    = 10240000;          // 500*128*8
static constexpr size_t OFF_TQD   = 10752000;          // 100*128*8
static constexpr size_t OFF_TCD   = 10854400;          // 100*128*8
static constexpr size_t OFF_TCOK  = 10956800;          // 2*128*4 (kip co part, -L2E)
static constexpr size_t OFF_TP1   = 10957824;          // 2*128*4, scaled -L2E
static constexpr size_t OFF_TP2   = 10958848;          // 2*128*4, scaled -2*L2E
static constexpr size_t OFF_TMPA  = 10959872;          // 100*128*4 raw Eqd@Wki2
static constexpr size_t OFF_TMPB  = 11011072;          // 100*128*4 raw Ecd@Wki3
static constexpr size_t OFF_WFRAG = 11062272;          // 5*128*128*2 (pre-scaled bf16)
static constexpr size_t TOTAL_WS  = 11226112;

// fallback scratch if harness workspace is too small
__device__ unsigned char g_fb[TOTAL_WS];

// ---------------- helpers ----------------
__device__ __forceinline__ unsigned short f2bf(float f) {
    union { float f; uint32_t u; } v; v.f = f;
    uint32_t u = v.u;
    uint32_t r = u + 0x7FFFu + ((u >> 16) & 1u);
    return (unsigned short)(r >> 16);
}
__device__ __forceinline__ float fsig(float z) {
    return __builtin_amdgcn_rcpf(1.0f + __expf(-z));
}
// pack 2 f32 -> 2 bf16 (RTNE): dst.lo = cvt(lo), dst.hi = cvt(hi)
__device__ __forceinline__ uint32_t cvtpk(float lo, float hi) {
    uint32_t r;
    asm("v_cvt_pk_bf16_f32 %0, %1, %2" : "=v"(r) : "v"(lo), "v"(hi));
    return r;
}
// barrier that only orders LDS traffic (prefetch loads stay in flight)
__device__ __forceinline__ void bar_lgkm() {
    asm volatile("s_waitcnt lgkmcnt(0)" ::: "memory");
    __builtin_amdgcn_s_barrier();
}
// sum over each 16-lane group via DPP (quad xor1, xor2, half-mirror, mirror)
__device__ __forceinline__ float sum16(float x) {
    int a = __float_as_int(x);
    int b = __builtin_amdgcn_update_dpp(a, a, 0xB1, 0xF, 0xF, false);   // quad xor1
    float s = x + __int_as_float(b);
    int c = __float_as_int(s);
    int d = __builtin_amdgcn_update_dpp(c, c, 0x4E, 0xF, 0xF, false);   // quad xor2
    s += __int_as_float(d);
    int e = __float_as_int(s);
    int f = __builtin_amdgcn_update_dpp(e, e, 0x141, 0xF, 0xF, false);  // row_half_mirror
    s += __int_as_float(f);
    int gg = __float_as_int(s);
    int hh = __builtin_amdgcn_update_dpp(gg, gg, 0x140, 0xF, 0xF, false); // row_mirror
    return s + __int_as_float(hh);
}

// ---------------- P1: per-table GEMM products (x-parts + raw ki tmps) ----------------
__global__ __launch_bounds__(128) void k_tables(
    const float* __restrict__ Eq, const float* __restrict__ Ec,
    const float* __restrict__ Eqd, const float* __restrict__ Ecd,
    const float* __restrict__ Ecorr,
    const float* __restrict__ Wx,  const float* __restrict__ bx,
    const float* __restrict__ Wpka1, const float* __restrict__ bpka1,
    const float* __restrict__ Wpka2, const float* __restrict__ bpka2,
    const float* __restrict__ Wki, const float* __restrict__ bki,
    float* __restrict__ TQ, float* __restrict__ TC,
    float* __restrict__ TQD, float* __restrict__ TCD,
    float* __restrict__ TCOk, float* __restrict__ Tp1, float* __restrict__ Tp2,
    float* __restrict__ tmpA, float* __restrict__ tmpB)
{
    int blk = blockIdx.x;
    const float* A; const float* W; const float* bias = nullptr; float* out; int row;
    int ostride = 1;
    float oscale = 1.0f;
    if      (blk < 10000) { A = Eq;    row = blk;          W = Wx;              bias = bx;    out = TQ;   ostride = 2; }
    else if (blk < 10500) { A = Ec;    row = blk - 10000;  W = Wx  + 128*128;                 out = TC;   ostride = 2; }
    else if (blk < 10600) { A = Eqd;   row = blk - 10500;  W = Wx  + 256*128;                 out = TQD;  ostride = 2; }
    else if (blk < 10700) { A = Ecd;   row = blk - 10600;  W = Wx  + 384*128;                 out = TCD;  ostride = 2; }
    else if (blk < 10800) { A = Eqd;   row = blk - 10700;  W = Wki + 256*128;                 out = tmpA; }
    else if (blk < 10900) { A = Ecd;   row = blk - 10800;  W = Wki + 384*128;                 out = tmpB; }
    else if (blk < 10902) { A = Ecorr; row = blk - 10900;  W = Wki + 128*128;   bias = bki;   out = TCOk; oscale = -L2E; }
    else if (blk < 10904) { A = Ecorr; row = blk - 10902;  W = Wpka1 + 128*128; bias = bpka1; out = Tp1;  oscale = -L2E; }
    else                  { A = Ecorr; row = blk - 10904;  W = Wpka2 + 128*128; bias = bpka2; out = Tp2;  oscale = -2.0f*L2E; }

    __shared__ float a[128];
    int c = threadIdx.x;
    a[c] = A[row * 128 + c];
    __syncthreads();
    float acc = bias ? bias[c] : 0.0f;
    #pragma unroll 8
    for (int k = 0; k < 128; ++k) acc += a[k] * W[k * 128 + c];
    out[(size_t)(row * 128 + c) * ostride] = acc * oscale;
}

// ---------------- P1b: kip-parts (.y) = (x-part @ Wki0 [+ raw tmp]) * -L2E ----------
__global__ __launch_bounds__(128) void k_tables2(
    const float* __restrict__ Wki,
    float* __restrict__ TQ, float* __restrict__ TC,
    float* __restrict__ TQD, float* __restrict__ TCD,
    const float* __restrict__ tmpA, const float* __restrict__ tmpB)
{
    int blk = blockIdx.x;
    float* base2; const float* tmp = nullptr; int row;
    if      (blk < 10000) { row = blk;          base2 = TQ  + (size_t)row * 256; }
    else if (blk < 10500) { row = blk - 10000;  base2 = TC  + (size_t)row * 256; }
    else if (blk < 10600) { row = blk - 10500;  base2 = TQD + (size_t)row * 256; tmp = tmpA + (size_t)row * 128; }
    else                  { row = blk - 10600;  base2 = TCD + (size_t)row * 256; tmp = tmpB + (size_t)row * 128; }
    __shared__ float a[128];
    int c = threadIdx.x;
    a[c] = base2[c * 2];          // x-part
    __syncthreads();
    float acc = tmp ? tmp[c] : 0.0f;
    #pragma unroll 8
    for (int k = 0; k < 128; ++k) acc += a[k] * Wki[k * 128 + c];
    base2[c * 2 + 1] = acc * (-L2E);
}

// ---------------- P0: weight matrices -> MFMA B-fragments (bf16, exp2-prescaled) ----
__global__ __launch_bounds__(64) void k_wfrag(
    const float* __restrict__ Wsdf1, const float* __restrict__ Wsdf2,
    const float* __restrict__ Wpka1, const float* __restrict__ Wpka2,
    const float* __restrict__ Wki, unsigned short* __restrict__ wfrag)
{
    int bid = blockIdx.x;                 // 5 * 8 * 4 = 160
    int m = bid >> 5, w = (bid >> 2) & 7, kt = bid & 3;
    const float* W = (m == 0) ? Wsdf1 : (m == 1) ? Wsdf2 : (m == 2) ? Wpka1 : (m == 3) ? Wpka2 : Wki;
    float sgn = (m == 0) ? -L2E : (m == 1) ? -2.0f*L2E : (m == 2) ? -L2E : (m == 3) ? -2.0f*L2E : L2E;
    int l = threadIdx.x;
    int cc = w * 16 + (l & 15);
    int k0 = kt * 32 + ((l >> 4) << 3);
    unsigned short v[8];
    #pragma unroll
    for (int j = 0; j < 8; ++j) v[j] = f2bf(sgn * W[(size_t)(k0 + j) * 128 + cc]);
    unsigned short* dst = wfrag + ((( (size_t)m * 8 + w) * 4 + kt) * 64 + l) * 8;
    #pragma unroll
    for (int j = 0; j < 8; ++j) dst[j] = v[j];
}

// ---------------- recurrence: 256 blocks x 512 threads (8 waves, 2 rows/block) --------
// R7/R9-verified core (dup-8 A-tile, 2-chain MFMA split, swizzled 2-row LDS) + inline
// gather with DEFERRED-SUM distance-2 pipeline: raw table loads for t+2 issued at iter
// top, kept as registers, summed only at consumption one full iteration later (~4300cy
// slack covers the idx->table dependent chain even on HBM misses). Inline y-finalize.
__global__ __launch_bounds__(512, 2) void k_rec(
    const int* __restrict__ qs, const int* __restrict__ cs,
    const int* __restrict__ qds, const int* __restrict__ cds, const int* __restrict__ corr,
    const float2* __restrict__ TQ, const float2* __restrict__ TC,
    const float2* __restrict__ TQD, const float2* __restrict__ TCD,
    const float* __restrict__ TCOk,
    const unsigned short* __restrict__ wfrag,
    const float* __restrict__ Tp1, const float* __restrict__ Tp2,
    const float* __restrict__ bsdf1, const float* __restrict__ bsdf2,
    const float* __restrict__ h0, float* __restrict__ y)
{
    int rb = blockIdx.x;
    int tid = threadIdx.x;
    int w = tid >> 6, l = tid & 63;
    int g = l >> 4, cl = l & 15;
    int col = w * 16 + cl;
    int row = g & 1;                 // owned logical row
    bool owner = (g < 2);            // non-dup lanes (do LDS writes / y partials)

    __shared__ __align__(16) unsigned short dbuf[256];   // 2 rows x 128 cols bf16
    __shared__ __align__(16) unsigned short sbuf[256];
    __shared__ __align__(16) float ybuf[2][2][8];        // [buf][row][wave]

    // weight B-fragments (5 matrices x 4 k-tiles), exp2-prescaled
    bf16x8 wf[5][4];
    #pragma unroll
    for (int m = 0; m < 5; ++m)
        #pragma unroll
        for (int kt = 0; kt < 4; ++kt)
            wf[m][kt] = *(const bf16x8*)(wfrag + ((((size_t)m * 8 + w) * 4 + kt) * 64 + l) * 8);

    float bs1 = bsdf1[col] * (-L2E);
    float bs2 = bsdf2[col] * (-2.0f * L2E);
    float tp1a = Tp1[col], tp1b = Tp1[128 + col];   // pre-scaled -L2E
    float tp2a = Tp2[col], tp2b = Tp2[128 + col];   // pre-scaled -2L2E

    float h = h0[(size_t)(rb * 2 + row) * 128 + col];

    // LDS byte addresses (swizzled; verified conflict-free reads R7/R9/R11)
    char* pdw = (char*)dbuf + row * 256 + ((col * 2) ^ (row << 6));
    char* psw = (char*)sbuf + row * 256 + ((col * 2) ^ (row << 6));
    const bf16x8* prd[4]; const bf16x8* prs[4];
    int rrow = cl & 1;
    #pragma unroll
    for (int kt = 0; kt < 4; ++kt) {
        int off = rrow * 256 + ((kt * 64 + g * 16) ^ (rrow << 6));
        prd[kt] = (const bf16x8*)((char*)dbuf + off);
        prs[kt] = (const bf16x8*)((char*)sbuf + off);
    }

    // inline gather base: this lane's row
    int boff = (rb * 2 + row) * SS;
    float* yrow = y + (size_t)(rb * 2) * SS;   // rows rb*2, rb*2+1

    // ---- prologue ----
    // gather(0): sums computed immediately (latency exposed once)
    float kip_c; unsigned int c_c;
    {
        int iq = qs[boff], ic = cs[boff], iqd = qds[boff], icd = cds[boff], ico = corr[boff];
        float2 q = TQ[(size_t)iq * 128 + col], c_ = TC[(size_t)ic * 128 + col];
        float2 qd = TQD[(size_t)iqd * 128 + col], cd = TCD[(size_t)icd * 128 + col];
        float co = TCOk[(size_t)ico * 128 + col];
        float x0 = q.x + c_.x + qd.x + cd.x;
        kip_c = q.y + c_.y + qd.y + cd.y + co;
        c_c = (unsigned int)ico & 1u;
        uint32_t pk = cvtpk(x0 - h, x0 - h);
        if (owner) *(unsigned short*)pdw = (unsigned short)pk;
    }
    // gather(1): RAW pipeline registers (summed at end of iter 0)
    float2 gq1, gc1, gqd1, gcd1; float gco1; int ico1;
    {
        int o1 = boff + 1;
        int iq = qs[o1], ic = cs[o1], iqd = qds[o1], icd = cds[o1];
        ico1 = corr[o1];
        gq1  = TQ [(size_t)iq  * 128 + col];
        gc1  = TC [(size_t)ic  * 128 + col];
        gqd1 = TQD[(size_t)iqd * 128 + col];
        gcd1 = TCD[(size_t)icd * 128 + col];
        gco1 = TCOk[(size_t)ico1 * 128 + col];
    }
    bar_lgkm();

    #pragma unroll 2
    for (int t = 0; t < TT; ++t) {
        // ---- issue raw gather for t+2 (consumed at end of NEXT iteration) ----
        int tp = t + 2; tp = (tp > 499) ? 499 : tp;   // stays within this row
        int op = boff + tp;
        int iq2 = qs[op], ic2 = cs[op], iqd2 = qds[op], icd2 = cds[op], ico2 = corr[op];
        float2 gq2  = TQ [(size_t)iq2  * 128 + col];
        float2 gc2  = TC [(size_t)ic2  * 128 + col];
        float2 gqd2 = TQD[(size_t)iqd2 * 128 + col];
        float2 gcd2 = TCD[(size_t)icd2 * 128 + col];
        float  gco2 = TCOk[(size_t)ico2 * 128 + col];

        // ---- phase 1: s1,s2 = d@Wsdf (scaled); gd = d@(L2E*Wki0) ----
        f32x4 s1a = {bs1, bs1, bs1, bs1}, s1b = {0.f, 0.f, 0.f, 0.f};
        f32x4 s2a = {bs2, bs2, bs2, bs2}, s2b = {0.f, 0.f, 0.f, 0.f};
        f32x4 gda = {kip_c, kip_c, kip_c, kip_c}, gdb = {0.f, 0.f, 0.f, 0.f};
        {
            bf16x8 d0 = *prd[0], d1 = *prd[1], d2 = *prd[2], d3 = *prd[3];
            s1a = MFMA16(d0, wf[0][0], s1a); s2a = MFMA16(d0, wf[1][0], s2a); gda = MFMA16(d0, wf[4][0], gda);
            s1b = MFMA16(d2, wf[0][2], s1b); s2b = MFMA16(d2, wf[1][2], s2b); gdb = MFMA16(d2, wf[4][2], gdb);
            s1a = MFMA16(d1, wf[0][1], s1a); s2a = MFMA16(d1, wf[1][1], s2a); gda = MFMA16(d1, wf[4][1], gda);
            s1b = MFMA16(d3, wf[0][3], s1b); s2b = MFMA16(d3, wf[1][3], s2b); gdb = MFMA16(d3, wf[4][3], gdb);
        }
        float s1v = (row ? s1a[1] : s1a[0]) + (row ? s1b[1] : s1b[0]);
        float s2v = (row ? s2a[1] : s2a[0]) + (row ? s2b[1] : s2b[0]);
        float gdv = (row ? gda[1] : gda[0]) + (row ? gdb[1] : gdb[0]);
        float gv = __builtin_amdgcn_rcpf(1.0f + __builtin_amdgcn_exp2f(gdv));
        float e1 = __builtin_amdgcn_exp2f(s1v), e2 = __builtin_amdgcn_exp2f(s2v);
        float sdf = (1.0f - e2) * __builtin_amdgcn_rcpf((1.0f + e1) * (1.0f + e2));
        {
            uint32_t pk = cvtpk(sdf, sdf);
            if (owner) *(unsigned short*)psw = (unsigned short)pk;
        }
        bar_lgkm();

        // ---- finalize y(t-1): wave 0, lanes 0..1 reduce previous step's partials ----
        if (t > 0 && w == 0 && l < 2) {
            const float* yb = ybuf[(t - 1) & 1][l];
            float s = (yb[0] + yb[1]) + (yb[2] + yb[3]) + (yb[4] + yb[5]) + (yb[6] + yb[7]);
            yrow[(size_t)l * SS + (t - 1)] = fsig(s);
        }

        // ---- phase 2: p1,p2 = sdf@Wpka (scaled); bias via corr bit ----
        f32x4 p1a = {0.f, 0.f, 0.f, 0.f}, p1b = {0.f, 0.f, 0.f, 0.f};
        f32x4 p2a = {0.f, 0.f, 0.f, 0.f}, p2b = {0.f, 0.f, 0.f, 0.f};
        {
            bf16x8 f0 = *prs[0], f1 = *prs[1], f2 = *prs[2], f3 = *prs[3];
            p1a = MFMA16(f0, wf[2][0], p1a); p2a = MFMA16(f0, wf[3][0], p2a);
            p1b = MFMA16(f2, wf[2][2], p1b); p2b = MFMA16(f2, wf[3][2], p2b);
            p1a = MFMA16(f1, wf[2][1], p1a); p2a = MFMA16(f1, wf[3][1], p2a);
            p1b = MFMA16(f3, wf[2][3], p1b); p2b = MFMA16(f3, wf[3][3], p2b);
        }
        float p1v = (row ? p1a[1] : p1a[0]) + (row ? p1b[1] : p1b[0]);
        float p2v = (row ? p2a[1] : p2a[0]) + (row ? p2b[1] : p2b[0]);
        float t1 = c_c ? tp1b : tp1a;
        float t2 = c_c ? tp2b : tp2a;
        float e1p = __builtin_amdgcn_exp2f(p1v + t1), e2p = __builtin_amdgcn_exp2f(p2v + t2);
        float pka = (1.0f - e2p) * __builtin_amdgcn_rcpf((1.0f + e1p) * (1.0f + e2p));
        h = gv * (h - pka) + pka;

        // ---- consume RAW gather set 1 (loads issued one full iteration ago) ----
        float xn = (gq1.x + gc1.x) + (gqd1.x + gcd1.x);
        {
            uint32_t pk = cvtpk(xn - h, xn - h);
            if (owner) *(unsigned short*)pdw = (unsigned short)pk;
        }
        // ---- y partial (off critical path): 16-lane DPP sum -> LDS ybuf ----
        float yv = sum16(xn * h);
        if (owner && cl == 0) ybuf[t & 1][row][w] = yv;
        bar_lgkm();

        // ---- rotate: kip/corr for next iter from set 1; set 1 <- set 2 ----
        kip_c = (gq1.y + gc1.y) + (gqd1.y + gcd1.y) + gco1;
        c_c = (unsigned int)ico1 & 1u;
        gq1 = gq2; gc1 = gc2; gqd1 = gqd2; gcd1 = gcd2; gco1 = gco2; ico1 = ico2;
    }

    // epilogue: y(498) from ybuf, and y(:,499) = 0
    if (w == 0 && l < 2) {
        const float* yb = ybuf[(TT - 1) & 1][l];
        float s = (yb[0] + yb[1]) + (yb[2] + yb[3]) + (yb[4] + yb[5]) + (yb[6] + yb[7]);
        yrow[(size_t)l * SS + (TT - 1)] = fsig(s);
        yrow[(size_t)l * SS + TT] = 0.0f;
    }
}

// ---------------- launch ----------------
extern "C" void kernel_launch(void* const* d_in, const int* in_sizes, int n_in,
                              void* d_out, int out_size, void* d_ws, size_t ws_size,
                              hipStream_t stream) {
    const int* qs    = (const int*)d_in[0];
    const int* cs    = (const int*)d_in[1];
    const int* qds   = (const int*)d_in[2];
    const int* cds   = (const int*)d_in[3];
    const int* corr  = (const int*)d_in[4];
    const float* Eq    = (const float*)d_in[5];
    const float* Ec    = (const float*)d_in[6];
    const float* Eqd   = (const float*)d_in[7];
    const float* Ecd   = (const float*)d_in[8];
    const float* Ecorr = (const float*)d_in[9];
    const float* Wx    = (const float*)d_in[10];
    const float* bx    = (const float*)d_in[11];
    const float* Wsdf1 = (const float*)d_in[12];
    const float* bsdf1 = (const float*)d_in[13];
    const float* Wsdf2 = (const float*)d_in[14];
    const float* bsdf2 = (const float*)d_in[15];
    const float* Wpka1 = (const float*)d_in[16];
    const float* bpka1 = (const float*)d_in[17];
    const float* Wpka2 = (const float*)d_in[18];
    const float* bpka2 = (const float*)d_in[19];
    const float* Wki   = (const float*)d_in[20];
    const float* bki   = (const float*)d_in[21];
    const float* h0    = (const float*)d_in[22];

    char* base;
    if (ws_size >= TOTAL_WS) {
        base = (char*)d_ws;
    } else {
        void* p = nullptr;
        hipGetSymbolAddress(&p, HIP_SYMBOL(g_fb));
        base = (char*)p;
    }

    float* TQ    = (float*)(base + OFF_TQ);
    float* TC    = (float*)(base + OFF_TC);
    float* TQD   = (float*)(base + OFF_TQD);
    float* TCD   = (float*)(base + OFF_TCD);
    float* TCOk  = (float*)(base + OFF_TCOK);
    float* Tp1   = (float*)(base + OFF_TP1);
    float* Tp2   = (float*)(base + OFF_TP2);
    float* tmpA  = (float*)(base + OFF_TMPA);
    float* tmpB  = (float*)(base + OFF_TMPB);
    unsigned short* wfrag = (unsigned short*)(base + OFF_WFRAG);

    k_tables<<<10906, 128, 0, stream>>>(Eq, Ec, Eqd, Ecd, Ecorr, Wx, bx,
                                        Wpka1, bpka1, Wpka2, bpka2, Wki, bki,
                                        TQ, TC, TQD, TCD, TCOk, Tp1, Tp2, tmpA, tmpB);
    k_tables2<<<10700, 128, 0, stream>>>(Wki, TQ, TC, TQD, TCD, tmpA, tmpB);
    k_wfrag<<<160, 64, 0, stream>>>(Wsdf1, Wsdf2, Wpka1, Wpka2, Wki, wfrag);
    k_rec<<<NRB, 512, 0, stream>>>(qs, cs, qds, cds, corr,
                                   (const float2*)TQ, (const float2*)TC,
                                   (const float2*)TQD, (const float2*)TCD, TCOk,
                                   wfrag, Tp1, Tp2, bsdf1, bsdf2, h0, (float*)d_out);
}

// Round 13
// 502.421 us; speedup vs baseline: 1.0689x; 1.0689x over previous
//
#include <hip/hip_runtime.h>
#include <hip/hip_bf16.h>
#include <cstdint>
#include <cstddef>

// ---------------- problem constants ----------------
#define BB 512
#define SS 500
#define TT 499            // scan steps t = 0..498
#define NRB 256           // recurrence blocks (2 rows each)
#define L2E 1.4426950408889634f

typedef float  f32x4  __attribute__((ext_vector_type(4)));
typedef short  bf16x8 __attribute__((ext_vector_type(8)));

#define MFMA16(A, B, C) __builtin_amdgcn_mfma_f32_16x16x32_bf16((A), (B), (C), 0, 0, 0)

// ---------------- workspace layout (bytes) ----------------
// interleaved tables: element [row*128+col] = float2 { x-part, kip-part(-L2E-scaled) }
static constexpr size_t OFF_TQ    = 0;                 // 10000*128*8
static constexpr size_t OFF_TC    = 10240000;          // 500*128*8
static constexpr size_t OFF_TQD   = 10752000;          // 100*128*8
static constexpr size_t OFF_TCD   = 10854400;          // 100*128*8
static constexpr size_t OFF_TCOK  = 10956800;          // 2*128*4 (kip co part, -L2E)
static constexpr size_t OFF_TP1   = 10957824;          // 2*128*4, scaled -L2E
static constexpr size_t OFF_TP2   = 10958848;          // 2*128*4, scaled -2*L2E
static constexpr size_t OFF_TMPA  = 10959872;          // 100*128*4 raw Eqd@Wki2
static constexpr size_t OFF_TMPB  = 11011072;          // 100*128*4 raw Ecd@Wki3
static constexpr size_t OFF_WFRAG = 11062272;          // 5*128*128*2 (pre-scaled bf16)
static constexpr size_t OFF_CPK   = 11226112;          // 256*512 bytes
static constexpr size_t OFF_STRM  = 11357184;          // 500*512*128*4  u32{bf16 x|bf16 kip}
static constexpr size_t TOTAL_WS  = 142429184;

// fallback scratch if harness workspace is too small
__device__ unsigned char g_fb[TOTAL_WS];

// ---------------- helpers ----------------
__device__ __forceinline__ unsigned short f2bf(float f) {
    union { float f; uint32_t u; } v; v.f = f;
    uint32_t u = v.u;
    uint32_t r = u + 0x7FFFu + ((u >> 16) & 1u);
    return (unsigned short)(r >> 16);
}
__device__ __forceinline__ float fsig(float z) {
    return __builtin_amdgcn_rcpf(1.0f + __expf(-z));
}
// unpack u32 {hi: bf16 x | lo: bf16 kip}
__device__ __forceinline__ float upk_x(uint32_t p) { return __uint_as_float(p & 0xffff0000u); }
__device__ __forceinline__ float upk_k(uint32_t p) { return __uint_as_float(p << 16); }
// pack 2 f32 -> 2 bf16 (RTNE): dst.lo = cvt(lo), dst.hi = cvt(hi)
__device__ __forceinline__ uint32_t cvtpk(float lo, float hi) {
    uint32_t r;
    asm("v_cvt_pk_bf16_f32 %0, %1, %2" : "=v"(r) : "v"(lo), "v"(hi));
    return r;
}
// barrier that only orders LDS traffic (prefetch loads stay in flight)
__device__ __forceinline__ void bar_lgkm() {
    asm volatile("s_waitcnt lgkmcnt(0)" ::: "memory");
    __builtin_amdgcn_s_barrier();
}
// sum over each 16-lane group via DPP (quad xor1, xor2, half-mirror, mirror)
__device__ __forceinline__ float sum16(float x) {
    int a = __float_as_int(x);
    int b = __builtin_amdgcn_update_dpp(a, a, 0xB1, 0xF, 0xF, false);   // quad xor1
    float s = x + __int_as_float(b);
    int c = __float_as_int(s);
    int d = __builtin_amdgcn_update_dpp(c, c, 0x4E, 0xF, 0xF, false);   // quad xor2
    s += __int_as_float(d);
    int e = __float_as_int(s);
    int f = __builtin_amdgcn_update_dpp(e, e, 0x141, 0xF, 0xF, false);  // row_half_mirror
    s += __int_as_float(f);
    int gg = __float_as_int(s);
    int hh = __builtin_amdgcn_update_dpp(gg, gg, 0x140, 0xF, 0xF, false); // row_mirror
    return s + __int_as_float(hh);
}

// ---------------- P1: per-table GEMM products (x-parts + raw ki tmps) ----------------
__global__ __launch_bounds__(128) void k_tables(
    const float* __restrict__ Eq, const float* __restrict__ Ec,
    const float* __restrict__ Eqd, const float* __restrict__ Ecd,
    const float* __restrict__ Ecorr,
    const float* __restrict__ Wx,  const float* __restrict__ bx,
    const float* __restrict__ Wpka1, const float* __restrict__ bpka1,
    const float* __restrict__ Wpka2, const float* __restrict__ bpka2,
    const float* __restrict__ Wki, const float* __restrict__ bki,
    float* __restrict__ TQ, float* __restrict__ TC,
    float* __restrict__ TQD, float* __restrict__ TCD,
    float* __restrict__ TCOk, float* __restrict__ Tp1, float* __restrict__ Tp2,
    float* __restrict__ tmpA, float* __restrict__ tmpB)
{
    int blk = blockIdx.x;
    const float* A; const float* W; const float* bias = nullptr; float* out; int row;
    int ostride = 1;
    float oscale = 1.0f;
    if      (blk < 10000) { A = Eq;    row = blk;          W = Wx;              bias = bx;    out = TQ;   ostride = 2; }
    else if (blk < 10500) { A = Ec;    row = blk - 10000;  W = Wx  + 128*128;                 out = TC;   ostride = 2; }
    else if (blk < 10600) { A = Eqd;   row = blk - 10500;  W = Wx  + 256*128;                 out = TQD;  ostride = 2; }
    else if (blk < 10700) { A = Ecd;   row = blk - 10600;  W = Wx  + 384*128;                 out = TCD;  ostride = 2; }
    else if (blk < 10800) { A = Eqd;   row = blk - 10700;  W = Wki + 256*128;                 out = tmpA; }
    else if (blk < 10900) { A = Ecd;   row = blk - 10800;  W = Wki + 384*128;                 out = tmpB; }
    else if (blk < 10902) { A = Ecorr; row = blk - 10900;  W = Wki + 128*128;   bias = bki;   out = TCOk; oscale = -L2E; }
    else if (blk < 10904) { A = Ecorr; row = blk - 10902;  W = Wpka1 + 128*128; bias = bpka1; out = Tp1;  oscale = -L2E; }
    else                  { A = Ecorr; row = blk - 10904;  W = Wpka2 + 128*128; bias = bpka2; out = Tp2;  oscale = -2.0f*L2E; }

    __shared__ float a[128];
    int c = threadIdx.x;
    a[c] = A[row * 128 + c];
    __syncthreads();
    float acc = bias ? bias[c] : 0.0f;
    #pragma unroll 8
    for (int k = 0; k < 128; ++k) acc += a[k] * W[k * 128 + c];
    out[(size_t)(row * 128 + c) * ostride] = acc * oscale;
}

// ---------------- P1b: kip-parts (.y) = (x-part @ Wki0 [+ raw tmp]) * -L2E ----------
__global__ __launch_bounds__(128) void k_tables2(
    const float* __restrict__ Wki,
    float* __restrict__ TQ, float* __restrict__ TC,
    float* __restrict__ TQD, float* __restrict__ TCD,
    const float* __restrict__ tmpA, const float* __restrict__ tmpB)
{
    int blk = blockIdx.x;
    float* base2; const float* tmp = nullptr; int row;
    if      (blk < 10000) { row = blk;          base2 = TQ  + (size_t)row * 256; }
    else if (blk < 10500) { row = blk - 10000;  base2 = TC  + (size_t)row * 256; }
    else if (blk < 10600) { row = blk - 10500;  base2 = TQD + (size_t)row * 256; tmp = tmpA + (size_t)row * 128; }
    else                  { row = blk - 10600;  base2 = TCD + (size_t)row * 256; tmp = tmpB + (size_t)row * 128; }
    __shared__ float a[128];
    int c = threadIdx.x;
    a[c] = base2[c * 2];          // x-part
    __syncthreads();
    float acc = tmp ? tmp[c] : 0.0f;
    #pragma unroll 8
    for (int k = 0; k < 128; ++k) acc += a[k] * Wki[k * 128 + c];
    base2[c * 2 + 1] = acc * (-L2E);
}

// ---------------- P0: weight matrices -> MFMA B-fragments (bf16, exp2-prescaled) ----
__global__ __launch_bounds__(64) void k_wfrag(
    const float* __restrict__ Wsdf1, const float* __restrict__ Wsdf2,
    const float* __restrict__ Wpka1, const float* __restrict__ Wpka2,
    const float* __restrict__ Wki, unsigned short* __restrict__ wfrag)
{
    int bid = blockIdx.x;                 // 5 * 8 * 4 = 160
    int m = bid >> 5, w = (bid >> 2) & 7, kt = bid & 3;
    const float* W = (m == 0) ? Wsdf1 : (m == 1) ? Wsdf2 : (m == 2) ? Wpka1 : (m == 3) ? Wpka2 : Wki;
    float sgn = (m == 0) ? -L2E : (m == 1) ? -2.0f*L2E : (m == 2) ? -L2E : (m == 3) ? -2.0f*L2E : L2E;
    int l = threadIdx.x;
    int cc = w * 16 + (l & 15);
    int k0 = kt * 32 + ((l >> 4) << 3);
    unsigned short v[8];
    #pragma unroll
    for (int j = 0; j < 8; ++j) v[j] = f2bf(sgn * W[(size_t)(k0 + j) * 128 + cc]);
    unsigned short* dst = wfrag + ((( (size_t)m * 8 + w) * 4 + kt) * 64 + l) * 8;
    #pragma unroll
    for (int j = 0; j < 8; ++j) dst[j] = v[j];
}

// ---------------- P2: materialize packed stream[t][b][col] = u32{bf16 x | bf16 kip} --
__global__ __launch_bounds__(512) void k_gather(
    const int* __restrict__ qs, const int* __restrict__ cs,
    const int* __restrict__ qds, const int* __restrict__ cds, const int* __restrict__ corr,
    const float2* __restrict__ TQ, const float2* __restrict__ TC,
    const float2* __restrict__ TQD, const float2* __restrict__ TCD,
    const float* __restrict__ TCOk,
    uint32_t* __restrict__ strm, unsigned char* __restrict__ cpk)
{
    int bid = blockIdx.x;            // bid = t*128 + chunk
    int t = bid >> 7, chunk = bid & 127;
    int tid = threadIdx.x;
    int b = chunk * 4 + (tid >> 7);  // 4 batch rows per block
    int col = tid & 127;

    int iq  = qs  [(size_t)b * SS + t];
    int ic  = cs  [(size_t)b * SS + t];
    int iqd = qds [(size_t)b * SS + t];
    int icd = cds [(size_t)b * SS + t];
    int ico = corr[(size_t)b * SS + t];

    float2 q  = TQ [(size_t)iq  * 128 + col];
    float2 c_ = TC [(size_t)ic  * 128 + col];
    float2 qd = TQD[(size_t)iqd * 128 + col];
    float2 cd = TCD[(size_t)icd * 128 + col];
    float  co = TCOk[(size_t)ico * 128 + col];

    float xs = q.x + c_.x + qd.x + cd.x;
    float ks = q.y + c_.y + qd.y + cd.y + co;
    strm[((size_t)t * BB + b) * 128 + col] = cvtpk(ks, xs);   // lo=kip, hi=x

    if (tid < 2) {   // rb = chunk*2 + tid covers b's [chunk*4, chunk*4+4)
        int rb = chunk * 2 + tid;
        unsigned char bpk = (unsigned char)((corr[(size_t)(rb * 2) * SS + t] & 1)
                          | ((corr[(size_t)(rb * 2 + 1) * SS + t] & 1) << 1));
        cpk[(size_t)rb * 512 + t] = bpk;
    }
}

// ---------------- recurrence: 256 blocks x 512 threads (8 waves, 2 rows/block) --------
// R7-verified core (dup-8 A-tile, 2-chain MFMA split, swizzled 2-row LDS) + packed
// bf16 stream (1 dword/lane/step, loaded at iter top, consumed ~1500cy later) + inline
// y-finalization (no k_yfinal / ypart round-trip) + kip folded into MFMA C-init.
__global__ __launch_bounds__(512, 2) void k_rec(
    const uint32_t* __restrict__ strm, const unsigned char* __restrict__ cpkg,
    const unsigned short* __restrict__ wfrag,
    const float* __restrict__ Tp1, const float* __restrict__ Tp2,
    const float* __restrict__ bsdf1, const float* __restrict__ bsdf2,
    const float* __restrict__ h0, float* __restrict__ y)
{
    int rb = blockIdx.x;
    int tid = threadIdx.x;
    int w = tid >> 6, l = tid & 63;
    int g = l >> 4, cl = l & 15;
    int col = w * 16 + cl;
    int row = g & 1;                 // owned logical row
    bool owner = (g < 2);            // non-dup lanes (do LDS writes / y partials)

    __shared__ __align__(16) unsigned short dbuf[256];   // 2 rows x 128 cols bf16
    __shared__ __align__(16) unsigned short sbuf[256];
    __shared__ __align__(16) float ybuf[2][2][8];        // [buf][row][wave]

    // weight B-fragments (5 matrices x 4 k-tiles), exp2-prescaled
    bf16x8 wf[5][4];
    #pragma unroll
    for (int m = 0; m < 5; ++m)
        #pragma unroll
        for (int kt = 0; kt < 4; ++kt)
            wf[m][kt] = *(const bf16x8*)(wfrag + ((((size_t)m * 8 + w) * 4 + kt) * 64 + l) * 8);

    float bs1 = bsdf1[col] * (-L2E);
    float bs2 = bsdf2[col] * (-2.0f * L2E);
    float tp1a = Tp1[col], tp1b = Tp1[128 + col];   // pre-scaled -L2E
    float tp2a = Tp2[col], tp2b = Tp2[128 + col];   // pre-scaled -2L2E

    float h = h0[(size_t)(rb * 2 + row) * 128 + col];

    // LDS byte addresses (swizzled; verified conflict-free reads R7/R9/R11)
    char* pdw = (char*)dbuf + row * 256 + ((col * 2) ^ (row << 6));
    char* psw = (char*)sbuf + row * 256 + ((col * 2) ^ (row << 6));
    const bf16x8* prd[4]; const bf16x8* prs[4];
    int rrow = cl & 1;
    #pragma unroll
    for (int kt = 0; kt < 4; ++kt) {
        int off = rrow * 256 + ((kt * 64 + g * 16) ^ (rrow << 6));
        prd[kt] = (const bf16x8*)((char*)dbuf + off);
        prs[kt] = (const bf16x8*)((char*)sbuf + off);
    }

    const size_t TSTR = (size_t)BB * 128;   // per-t stride in u32 elements
    const uint32_t* sp = strm + (size_t)(rb * 2 + row) * 128 + col;
    const unsigned char* cp = cpkg + (size_t)rb * 512;

    float* yrow = y + (size_t)(rb * 2) * SS;   // rows rb*2, rb*2+1

    // prologue: t=0 stream word; write d0
    float kip_c; unsigned int c_c;
    {
        uint32_t p0 = sp[0];
        kip_c = upk_k(p0);
        c_c = (cp[0] >> row) & 1u;
        float x0 = upk_x(p0);
        uint32_t pk = cvtpk(x0 - h, x0 - h);
        if (owner) *(unsigned short*)pdw = (unsigned short)pk;
    }
    bar_lgkm();

    #pragma unroll 2
    for (int t = 0; t < TT; ++t) {
        // ---- stream load for t+1 (consumed at end of this iter, ~1500cy slack) ----
        uint32_t pkN = sp[(size_t)(t + 1) * TSTR];
        unsigned char cN = cp[t + 1];

        // ---- phase 1: s1,s2 = d@Wsdf (scaled); gd = kip + d@(L2E*Wki0) ----
        f32x4 s1a = {bs1, bs1, bs1, bs1}, s1b = {0.f, 0.f, 0.f, 0.f};
        f32x4 s2a = {bs2, bs2, bs2, bs2}, s2b = {0.f, 0.f, 0.f, 0.f};
        f32x4 gda = {kip_c, kip_c, kip_c, kip_c}, gdb = {0.f, 0.f, 0.f, 0.f};
        {
            bf16x8 d0 = *prd[0], d1 = *prd[1], d2 = *prd[2], d3 = *prd[3];
            s1a = MFMA16(d0, wf[0][0], s1a); s2a = MFMA16(d0, wf[1][0], s2a); gda = MFMA16(d0, wf[4][0], gda);
            s1b = MFMA16(d2, wf[0][2], s1b); s2b = MFMA16(d2, wf[1][2], s2b); gdb = MFMA16(d2, wf[4][2], gdb);
            s1a = MFMA16(d1, wf[0][1], s1a); s2a = MFMA16(d1, wf[1][1], s2a); gda = MFMA16(d1, wf[4][1], gda);
            s1b = MFMA16(d3, wf[0][3], s1b); s2b = MFMA16(d3, wf[1][3], s2b); gdb = MFMA16(d3, wf[4][3], gdb);
        }
        float s1v = (row ? s1a[1] : s1a[0]) + (row ? s1b[1] : s1b[0]);
        float s2v = (row ? s2a[1] : s2a[0]) + (row ? s2b[1] : s2b[0]);
        float gdv = (row ? gda[1] : gda[0]) + (row ? gdb[1] : gdb[0]);
        float gv = __builtin_amdgcn_rcpf(1.0f + __builtin_amdgcn_exp2f(gdv));
        float e1 = __builtin_amdgcn_exp2f(s1v), e2 = __builtin_amdgcn_exp2f(s2v);
        float sdf = (1.0f - e2) * __builtin_amdgcn_rcpf((1.0f + e1) * (1.0f + e2));
        {
            uint32_t pk = cvtpk(sdf, sdf);
            if (owner) *(unsigned short*)psw = (unsigned short)pk;
        }
        bar_lgkm();

        // ---- finalize y(t-1): wave 0, lanes 0..1 reduce previous step's partials ----
        if (t > 0 && w == 0 && l < 2) {
            const float* yb = ybuf[(t - 1) & 1][l];
            float s = (yb[0] + yb[1]) + (yb[2] + yb[3]) + (yb[4] + yb[5]) + (yb[6] + yb[7]);
            yrow[(size_t)l * SS + (t - 1)] = fsig(s);
        }

        // ---- phase 2: p1,p2 = sdf@Wpka (scaled); bias via corr bit ----
        f32x4 p1a = {0.f, 0.f, 0.f, 0.f}, p1b = {0.f, 0.f, 0.f, 0.f};
        f32x4 p2a = {0.f, 0.f, 0.f, 0.f}, p2b = {0.f, 0.f, 0.f, 0.f};
        {
            bf16x8 f0 = *prs[0], f1 = *prs[1], f2 = *prs[2], f3 = *prs[3];
            p1a = MFMA16(f0, wf[2][0], p1a); p2a = MFMA16(f0, wf[3][0], p2a);
            p1b = MFMA16(f2, wf[2][2], p1b); p2b = MFMA16(f2, wf[3][2], p2b);
            p1a = MFMA16(f1, wf[2][1], p1a); p2a = MFMA16(f1, wf[3][1], p2a);
            p1b = MFMA16(f3, wf[2][3], p1b); p2b = MFMA16(f3, wf[3][3], p2b);
        }
        float p1v = (row ? p1a[1] : p1a[0]) + (row ? p1b[1] : p1b[0]);
        float p2v = (row ? p2a[1] : p2a[0]) + (row ? p2b[1] : p2b[0]);
        float t1 = c_c ? tp1b : tp1a;
        float t2 = c_c ? tp2b : tp2a;
        float e1p = __builtin_amdgcn_exp2f(p1v + t1), e2p = __builtin_amdgcn_exp2f(p2v + t2);
        float pka = (1.0f - e2p) * __builtin_amdgcn_rcpf((1.0f + e1p) * (1.0f + e2p));
        h = gv * (h - pka) + pka;

        // ---- d-write for step t+1 IMMEDIATELY (critical path) ----
        float xn = upk_x(pkN);
        {
            uint32_t pk = cvtpk(xn - h, xn - h);
            if (owner) *(unsigned short*)pdw = (unsigned short)pk;
        }
        // ---- y partial (off critical path): 16-lane DPP sum -> LDS ybuf ----
        float yv = sum16(xn * h);
        if (owner && cl == 0) ybuf[t & 1][row][w] = yv;
        bar_lgkm();

        // rotate: kip/corr for next iter
        kip_c = upk_k(pkN);
        c_c = ((unsigned int)cN >> row) & 1u;
    }

    // epilogue: y(498) from ybuf, and y(:,499) = 0
    if (w == 0 && l < 2) {
        const float* yb = ybuf[(TT - 1) & 1][l];
        float s = (yb[0] + yb[1]) + (yb[2] + yb[3]) + (yb[4] + yb[5]) + (yb[6] + yb[7]);
        yrow[(size_t)l * SS + (TT - 1)] = fsig(s);
        yrow[(size_t)l * SS + TT] = 0.0f;
    }
}

// ---------------- launch ----------------
extern "C" void kernel_launch(void* const* d_in, const int* in_sizes, int n_in,
                              void* d_out, int out_size, void* d_ws, size_t ws_size,
                              hipStream_t stream) {
    const int* qs    = (const int*)d_in[0];
    const int* cs    = (const int*)d_in[1];
    const int* qds   = (const int*)d_in[2];
    const int* cds   = (const int*)d_in[3];
    const int* corr  = (const int*)d_in[4];
    const float* Eq    = (const float*)d_in[5];
    const float* Ec    = (const float*)d_in[6];
    const float* Eqd   = (const float*)d_in[7];
    const float* Ecd   = (const float*)d_in[8];
    const float* Ecorr = (const float*)d_in[9];
    const float* Wx    = (const float*)d_in[10];
    const float* bx    = (const float*)d_in[11];
    const float* Wsdf1 = (const float*)d_in[12];
    const float* bsdf1 = (const float*)d_in[13];
    const float* Wsdf2 = (const float*)d_in[14];
    const float* bsdf2 = (const float*)d_in[15];
    const float* Wpka1 = (const float*)d_in[16];
    const float* bpka1 = (const float*)d_in[17];
    const float* Wpka2 = (const float*)d_in[18];
    const float* bpka2 = (const float*)d_in[19];
    const float* Wki   = (const float*)d_in[20];
    const float* bki   = (const float*)d_in[21];
    const float* h0    = (const float*)d_in[22];

    char* base;
    if (ws_size >= TOTAL_WS) {
        base = (char*)d_ws;
    } else {
        void* p = nullptr;
        hipGetSymbolAddress(&p, HIP_SYMBOL(g_fb));
        base = (char*)p;
    }

    float* TQ    = (float*)(base + OFF_TQ);
    float* TC    = (float*)(base + OFF_TC);
    float* TQD   = (float*)(base + OFF_TQD);
    float* TCD   = (float*)(base + OFF_TCD);
    float* TCOk  = (float*)(base + OFF_TCOK);
    float* Tp1   = (float*)(base + OFF_TP1);
    float* Tp2   = (float*)(base + OFF_TP2);
    float* tmpA  = (float*)(base + OFF_TMPA);
    float* tmpB  = (float*)(base + OFF_TMPB);
    unsigned short* wfrag = (unsigned short*)(base + OFF_WFRAG);
    unsigned char*  cpk   = (unsigned char*)(base + OFF_CPK);
    uint32_t* strm = (uint32_t*)(base + OFF_STRM);

    k_tables<<<10906, 128, 0, stream>>>(Eq, Ec, Eqd, Ecd, Ecorr, Wx, bx,
                                        Wpka1, bpka1, Wpka2, bpka2, Wki, bki,
                                        TQ, TC, TQD, TCD, TCOk, Tp1, Tp2, tmpA, tmpB);
    k_tables2<<<10700, 128, 0, stream>>>(Wki, TQ, TC, TQD, TCD, tmpA, tmpB);
    k_wfrag<<<160, 64, 0, stream>>>(Wsdf1, Wsdf2, Wpka1, Wpka2, Wki, wfrag);
    k_gather<<<SS * 128, 512, 0, stream>>>(qs, cs, qds, cds, corr,
                                           (const float2*)TQ, (const float2*)TC,
                                           (const float2*)TQD, (const float2*)TCD, TCOk,
                                           strm, cpk);
    k_rec<<<NRB, 512, 0, stream>>>(strm, cpk, wfrag, Tp1, Tp2,
                                   bsdf1, bsdf2, h0, (float*)d_out);
}

// Round 14
// 496.487 us; speedup vs baseline: 1.0817x; 1.0120x over previous
//
#include <hip/hip_runtime.h>
#include <hip/hip_bf16.h>
#include <cstdint>
#include <cstddef>

// ---------------- problem constants ----------------
#define BB 512
#define SS 500
#define TT 499            // scan steps t = 0..498
#define NRB 256           // recurrence blocks (2 rows each)
#define L2E 1.4426950408889634f

typedef float  f32x4  __attribute__((ext_vector_type(4)));
typedef short  bf16x8 __attribute__((ext_vector_type(8)));

#define MFMA16(A, B, C) __builtin_amdgcn_mfma_f32_16x16x32_bf16((A), (B), (C), 0, 0, 0)

// ---------------- workspace layout (bytes) ----------------
// interleaved tables: element [row*128+col] = float2 { x-part, kip-part(-L2E-scaled) }
static constexpr size_t OFF_TQ    = 0;                 // 10000*128*8
static constexpr size_t OFF_TC    = 10240000;          // 500*128*8
static constexpr size_t OFF_TQD   = 10752000;          // 100*128*8
static constexpr size_t OFF_TCD   = 10854400;          // 100*128*8
static constexpr size_t OFF_TCOK  = 10956800;          // 2*128*4 (kip co part, -L2E)
static constexpr size_t OFF_TP1   = 10957824;          // 2*128*4, scaled -L2E
static constexpr size_t OFF_TP2   = 10958848;          // 2*128*4, scaled -2*L2E
static constexpr size_t OFF_WCOMB = 10959872;          // 4*128*128*4 combined kip weights
static constexpr size_t OFF_BKQ   = 11222016;          // 128*4 (bx @ Wki0), pad
static constexpr size_t OFF_WFRAG = 11223040;          // 5*128*128*2 (pre-scaled bf16)
static constexpr size_t OFF_CPK   = 11386880;          // 256*512 bytes
static constexpr size_t OFF_STRM  = 11517952;          // 500*512*128*4  u32{bf16 x|bf16 kip}
static constexpr size_t TOTAL_WS  = 142589952;

// fallback scratch if harness workspace is too small
__device__ unsigned char g_fb[TOTAL_WS];

// ---------------- helpers ----------------
__device__ __forceinline__ unsigned short f2bf(float f) {
    union { float f; uint32_t u; } v; v.f = f;
    uint32_t u = v.u;
    uint32_t r = u + 0x7FFFu + ((u >> 16) & 1u);
    return (unsigned short)(r >> 16);
}
__device__ __forceinline__ float fsig(float z) {
    return __builtin_amdgcn_rcpf(1.0f + __expf(-z));
}
// unpack u32 {hi: bf16 x | lo: bf16 kip}
__device__ __forceinline__ float upk_x(uint32_t p) { return __uint_as_float(p & 0xffff0000u); }
__device__ __forceinline__ float upk_k(uint32_t p) { return __uint_as_float(p << 16); }
// pack 2 f32 -> 2 bf16 (RTNE): dst.lo = cvt(lo), dst.hi = cvt(hi)
__device__ __forceinline__ uint32_t cvtpk(float lo, float hi) {
    uint32_t r;
    asm("v_cvt_pk_bf16_f32 %0, %1, %2" : "=v"(r) : "v"(lo), "v"(hi));
    return r;
}
// barrier that only orders LDS traffic (prefetch loads stay in flight)
__device__ __forceinline__ void bar_lgkm() {
    asm volatile("s_waitcnt lgkmcnt(0)" ::: "memory");
    __builtin_amdgcn_s_barrier();
}
// sum over each 16-lane group via DPP (quad xor1, xor2, half-mirror, mirror)
__device__ __forceinline__ float sum16(float x) {
    int a = __float_as_int(x);
    int b = __builtin_amdgcn_update_dpp(a, a, 0xB1, 0xF, 0xF, false);   // quad xor1
    float s = x + __int_as_float(b);
    int c = __float_as_int(s);
    int d = __builtin_amdgcn_update_dpp(c, c, 0x4E, 0xF, 0xF, false);   // quad xor2
    s += __int_as_float(d);
    int e = __float_as_int(s);
    int f = __builtin_amdgcn_update_dpp(e, e, 0x141, 0xF, 0xF, false);  // row_half_mirror
    s += __int_as_float(f);
    int gg = __float_as_int(s);
    int hh = __builtin_amdgcn_update_dpp(gg, gg, 0x140, 0xF, 0xF, false); // row_mirror
    return s + __int_as_float(hh);
}

// ---------------- P0a: combined kip weights -----------------------------------------
// blk<512: Wcomb[m][r][c] = sum_k Wx[m*128+r][k]*Wki0[k][c]  (+ Wki2/Wki3 for m=2/3)
// blk==512: bkq[c] = sum_k bx[k]*Wki0[k][c]
__global__ __launch_bounds__(128) void k_wcomb(
    const float* __restrict__ Wx, const float* __restrict__ bx,
    const float* __restrict__ Wki,
    float* __restrict__ Wcomb, float* __restrict__ bkq)
{
    int blk = blockIdx.x;
    int c = threadIdx.x;
    __shared__ float a[128];
    float acc;
    if (blk < 512) {
        int m = blk >> 7, r = blk & 127;
        a[c] = Wx[(size_t)(m * 128 + r) * 128 + c];
        acc = (m == 2) ? Wki[(size_t)(256 + r) * 128 + c]
            : (m == 3) ? Wki[(size_t)(384 + r) * 128 + c] : 0.0f;
        __syncthreads();
        #pragma unroll 8
        for (int k = 0; k < 128; ++k) acc += a[k] * Wki[k * 128 + c];
        Wcomb[(size_t)(m * 128 + (blk & 127)) * 128 + c] = acc;
    } else {
        a[c] = bx[c];
        acc = 0.0f;
        __syncthreads();
        #pragma unroll 8
        for (int k = 0; k < 128; ++k) acc += a[k] * Wki[k * 128 + c];
        bkq[c] = acc;
    }
}

// ---------------- P1: merged table build (x + kip in one pass, 16 rows/block) --------
// blocks: [0,625) TQ | [625,657) TC | [657,664) TQD | [664,671) TCD | [671,677) specials
__global__ __launch_bounds__(128) void k_tables(
    const float* __restrict__ Eq, const float* __restrict__ Ec,
    const float* __restrict__ Eqd, const float* __restrict__ Ecd,
    const float* __restrict__ Ecorr,
    const float* __restrict__ Wx,  const float* __restrict__ bx,
    const float* __restrict__ Wpka1, const float* __restrict__ bpka1,
    const float* __restrict__ Wpka2, const float* __restrict__ bpka2,
    const float* __restrict__ Wki, const float* __restrict__ bki,
    const float* __restrict__ Wcomb, const float* __restrict__ bkq,
    float2* __restrict__ TQ, float2* __restrict__ TC,
    float2* __restrict__ TQD, float2* __restrict__ TCD,
    float* __restrict__ TCOk, float* __restrict__ Tp1, float* __restrict__ Tp2)
{
    int blk = blockIdx.x;
    int c = threadIdx.x;

    if (blk >= 671) {   // specials: single-row scalar dots
        int s = blk - 671;
        int row = s & 1;
        const float* W; const float* bias; float* out; float osc;
        if      (s < 2) { W = Wki   + 128*128; bias = bki;   out = TCOk; osc = -L2E; }
        else if (s < 4) { W = Wpka1 + 128*128; bias = bpka1; out = Tp1;  osc = -L2E; }
        else            { W = Wpka2 + 128*128; bias = bpka2; out = Tp2;  osc = -2.0f*L2E; }
        __shared__ float a2[128];
        a2[c] = Ecorr[row * 128 + c];
        __syncthreads();
        float acc = bias[c];
        #pragma unroll 8
        for (int k = 0; k < 128; ++k) acc += a2[k] * W[k * 128 + c];
        out[row * 128 + c] = acc * osc;
        return;
    }

    const float* A; float2* out; int row0, nrows, m;
    if      (blk < 625) { m = 0; A = Eq;  out = TQ;  row0 = blk * 16;          nrows = 16; }
    else if (blk < 657) { m = 1; A = Ec;  out = TC;  row0 = (blk - 625) * 16;  nrows = (row0 + 16 <= 500) ? 16 : 500 - row0; }
    else if (blk < 664) { m = 2; A = Eqd; out = TQD; row0 = (blk - 657) * 16;  nrows = (row0 + 16 <= 100) ? 16 : 100 - row0; }
    else                { m = 3; A = Ecd; out = TCD; row0 = (blk - 664) * 16;  nrows = (row0 + 16 <= 100) ? 16 : 100 - row0; }

    const float* Wxp = Wx + (size_t)m * 128 * 128;
    const float* Wkp = Wcomb + (size_t)m * 128 * 128;

    __shared__ float as[16][128];
    #pragma unroll
    for (int r = 0; r < 16; ++r)
        as[r][c] = (r < nrows) ? A[(size_t)(row0 + r) * 128 + c] : 0.0f;
    __syncthreads();

    float accx[16], acck[16];
    float bx0 = (m == 0) ? bx[c] : 0.0f;
    float bk0 = (m == 0) ? bkq[c] : 0.0f;
    #pragma unroll
    for (int r = 0; r < 16; ++r) { accx[r] = bx0; acck[r] = bk0; }

    #pragma unroll 2
    for (int k = 0; k < 128; ++k) {
        float wx = Wxp[k * 128 + c];
        float wk = Wkp[k * 128 + c];
        #pragma unroll
        for (int r = 0; r < 16; ++r) {
            accx[r] += as[r][k] * wx;
            acck[r] += as[r][k] * wk;
        }
    }
    #pragma unroll
    for (int r = 0; r < 16; ++r) {
        if (r < nrows) {
            float2 o; o.x = accx[r]; o.y = acck[r] * (-L2E);
            out[(size_t)(row0 + r) * 128 + c] = o;
        }
    }
}

// ---------------- P0b: weight matrices -> MFMA B-fragments (bf16, exp2-prescaled) ----
__global__ __launch_bounds__(64) void k_wfrag(
    const float* __restrict__ Wsdf1, const float* __restrict__ Wsdf2,
    const float* __restrict__ Wpka1, const float* __restrict__ Wpka2,
    const float* __restrict__ Wki, unsigned short* __restrict__ wfrag)
{
    int bid = blockIdx.x;                 // 5 * 8 * 4 = 160
    int m = bid >> 5, w = (bid >> 2) & 7, kt = bid & 3;
    const float* W = (m == 0) ? Wsdf1 : (m == 1) ? Wsdf2 : (m == 2) ? Wpka1 : (m == 3) ? Wpka2 : Wki;
    float sgn = (m == 0) ? -L2E : (m == 1) ? -2.0f*L2E : (m == 2) ? -L2E : (m == 3) ? -2.0f*L2E : L2E;
    int l = threadIdx.x;
    int cc = w * 16 + (l & 15);
    int k0 = kt * 32 + ((l >> 4) << 3);
    unsigned short v[8];
    #pragma unroll
    for (int j = 0; j < 8; ++j) v[j] = f2bf(sgn * W[(size_t)(k0 + j) * 128 + cc]);
    unsigned short* dst = wfrag + ((( (size_t)m * 8 + w) * 4 + kt) * 64 + l) * 8;
    #pragma unroll
    for (int j = 0; j < 8; ++j) dst[j] = v[j];
}

// ---------------- P2: materialize packed stream[t][b][col] = u32{bf16 x | bf16 kip} --
__global__ __launch_bounds__(512) void k_gather(
    const int* __restrict__ qs, const int* __restrict__ cs,
    const int* __restrict__ qds, const int* __restrict__ cds, const int* __restrict__ corr,
    const float2* __restrict__ TQ, const float2* __restrict__ TC,
    const float2* __restrict__ TQD, const float2* __restrict__ TCD,
    const float* __restrict__ TCOk,
    uint32_t* __restrict__ strm, unsigned char* __restrict__ cpk)
{
    int bid = blockIdx.x;            // bid = t*128 + chunk
    int t = bid >> 7, chunk = bid & 127;
    int tid = threadIdx.x;
    int b = chunk * 4 + (tid >> 7);  // 4 batch rows per block
    int col = tid & 127;

    int iq  = qs  [(size_t)b * SS + t];
    int ic  = cs  [(size_t)b * SS + t];
    int iqd = qds [(size_t)b * SS + t];
    int icd = cds [(size_t)b * SS + t];
    int ico = corr[(size_t)b * SS + t];

    float2 q  = TQ [(size_t)iq  * 128 + col];
    float2 c_ = TC [(size_t)ic  * 128 + col];
    float2 qd = TQD[(size_t)iqd * 128 + col];
    float2 cd = TCD[(size_t)icd * 128 + col];
    float  co = TCOk[(size_t)ico * 128 + col];

    float xs = q.x + c_.x + qd.x + cd.x;
    float ks = q.y + c_.y + qd.y + cd.y + co;
    strm[((size_t)t * BB + b) * 128 + col] = cvtpk(ks, xs);   // lo=kip, hi=x

    if (tid < 2) {   // rb = chunk*2 + tid covers b's [chunk*4, chunk*4+4)
        int rb = chunk * 2 + tid;
        unsigned char bpk = (unsigned char)((corr[(size_t)(rb * 2) * SS + t] & 1)
                          | ((corr[(size_t)(rb * 2 + 1) * SS + t] & 1) << 1));
        cpk[(size_t)rb * 512 + t] = bpk;
    }
}

// ---------------- recurrence: 256 blocks x 512 threads (8 waves, 2 rows/block) --------
// R13-verified (byte-identical): dup-8 A-tile, 2-chain MFMA split, swizzled 2-row LDS,
// packed bf16 stream (1 dword/lane/step), inline y-finalization, kip in MFMA C-init.
__global__ __launch_bounds__(512, 2) void k_rec(
    const uint32_t* __restrict__ strm, const unsigned char* __restrict__ cpkg,
    const unsigned short* __restrict__ wfrag,
    const float* __restrict__ Tp1, const float* __restrict__ Tp2,
    const float* __restrict__ bsdf1, const float* __restrict__ bsdf2,
    const float* __restrict__ h0, float* __restrict__ y)
{
    int rb = blockIdx.x;
    int tid = threadIdx.x;
    int w = tid >> 6, l = tid & 63;
    int g = l >> 4, cl = l & 15;
    int col = w * 16 + cl;
    int row = g & 1;                 // owned logical row
    bool owner = (g < 2);            // non-dup lanes (do LDS writes / y partials)

    __shared__ __align__(16) unsigned short dbuf[256];   // 2 rows x 128 cols bf16
    __shared__ __align__(16) unsigned short sbuf[256];
    __shared__ __align__(16) float ybuf[2][2][8];        // [buf][row][wave]

    // weight B-fragments (5 matrices x 4 k-tiles), exp2-prescaled
    bf16x8 wf[5][4];
    #pragma unroll
    for (int m = 0; m < 5; ++m)
        #pragma unroll
        for (int kt = 0; kt < 4; ++kt)
            wf[m][kt] = *(const bf16x8*)(wfrag + ((((size_t)m * 8 + w) * 4 + kt) * 64 + l) * 8);

    float bs1 = bsdf1[col] * (-L2E);
    float bs2 = bsdf2[col] * (-2.0f * L2E);
    float tp1a = Tp1[col], tp1b = Tp1[128 + col];   // pre-scaled -L2E
    float tp2a = Tp2[col], tp2b = Tp2[128 + col];   // pre-scaled -2L2E

    float h = h0[(size_t)(rb * 2 + row) * 128 + col];

    // LDS byte addresses (swizzled; verified conflict-free reads R7/R9/R11/R13)
    char* pdw = (char*)dbuf + row * 256 + ((col * 2) ^ (row << 6));
    char* psw = (char*)sbuf + row * 256 + ((col * 2) ^ (row << 6));
    const bf16x8* prd[4]; const bf16x8* prs[4];
    int rrow = cl & 1;
    #pragma unroll
    for (int kt = 0; kt < 4; ++kt) {
        int off = rrow * 256 + ((kt * 64 + g * 16) ^ (rrow << 6));
        prd[kt] = (const bf16x8*)((char*)dbuf + off);
        prs[kt] = (const bf16x8*)((char*)sbuf + off);
    }

    const size_t TSTR = (size_t)BB * 128;   // per-t stride in u32 elements
    const uint32_t* sp = strm + (size_t)(rb * 2 + row) * 128 + col;
    const unsigned char* cp = cpkg + (size_t)rb * 512;

    float* yrow = y + (size_t)(rb * 2) * SS;   // rows rb*2, rb*2+1

    // prologue: t=0 stream word; write d0
    float kip_c; unsigned int c_c;
    {
        uint32_t p0 = sp[0];
        kip_c = upk_k(p0);
        c_c = (cp[0] >> row) & 1u;
        float x0 = upk_x(p0);
        uint32_t pk = cvtpk(x0 - h, x0 - h);
        if (owner) *(unsigned short*)pdw = (unsigned short)pk;
    }
    bar_lgkm();

    #pragma unroll 2
    for (int t = 0; t < TT; ++t) {
        // ---- stream load for t+1 (consumed at end of this iter, ~1500cy slack) ----
        uint32_t pkN = sp[(size_t)(t + 1) * TSTR];
        unsigned char cN = cp[t + 1];

        // ---- phase 1: s1,s2 = d@Wsdf (scaled); gd = kip + d@(L2E*Wki0) ----
        f32x4 s1a = {bs1, bs1, bs1, bs1}, s1b = {0.f, 0.f, 0.f, 0.f};
        f32x4 s2a = {bs2, bs2, bs2, bs2}, s2b = {0.f, 0.f, 0.f, 0.f};
        f32x4 gda = {kip_c, kip_c, kip_c, kip_c}, gdb = {0.f, 0.f, 0.f, 0.f};
        {
            bf16x8 d0 = *prd[0], d1 = *prd[1], d2 = *prd[2], d3 = *prd[3];
            s1a = MFMA16(d0, wf[0][0], s1a); s2a = MFMA16(d0, wf[1][0], s2a); gda = MFMA16(d0, wf[4][0], gda);
            s1b = MFMA16(d2, wf[0][2], s1b); s2b = MFMA16(d2, wf[1][2], s2b); gdb = MFMA16(d2, wf[4][2], gdb);
            s1a = MFMA16(d1, wf[0][1], s1a); s2a = MFMA16(d1, wf[1][1], s2a); gda = MFMA16(d1, wf[4][1], gda);
            s1b = MFMA16(d3, wf[0][3], s1b); s2b = MFMA16(d3, wf[1][3], s2b); gdb = MFMA16(d3, wf[4][3], gdb);
        }
        float s1v = (row ? s1a[1] : s1a[0]) + (row ? s1b[1] : s1b[0]);
        float s2v = (row ? s2a[1] : s2a[0]) + (row ? s2b[1] : s2b[0]);
        float gdv = (row ? gda[1] : gda[0]) + (row ? gdb[1] : gdb[0]);
        float gv = __builtin_amdgcn_rcpf(1.0f + __builtin_amdgcn_exp2f(gdv));
        float e1 = __builtin_amdgcn_exp2f(s1v), e2 = __builtin_amdgcn_exp2f(s2v);
        float sdf = (1.0f - e2) * __builtin_amdgcn_rcpf((1.0f + e1) * (1.0f + e2));
        {
            uint32_t pk = cvtpk(sdf, sdf);
            if (owner) *(unsigned short*)psw = (unsigned short)pk;
        }
        bar_lgkm();

        // ---- finalize y(t-1): wave 0, lanes 0..1 reduce previous step's partials ----
        if (t > 0 && w == 0 && l < 2) {
            const float* yb = ybuf[(t - 1) & 1][l];
            float s = (yb[0] + yb[1]) + (yb[2] + yb[3]) + (yb[4] + yb[5]) + (yb[6] + yb[7]);
            yrow[(size_t)l * SS + (t - 1)] = fsig(s);
        }

        // ---- phase 2: p1,p2 = sdf@Wpka (scaled); bias via corr bit ----
        f32x4 p1a = {0.f, 0.f, 0.f, 0.f}, p1b = {0.f, 0.f, 0.f, 0.f};
        f32x4 p2a = {0.f, 0.f, 0.f, 0.f}, p2b = {0.f, 0.f, 0.f, 0.f};
        {
            bf16x8 f0 = *prs[0], f1 = *prs[1], f2 = *prs[2], f3 = *prs[3];
            p1a = MFMA16(f0, wf[2][0], p1a); p2a = MFMA16(f0, wf[3][0], p2a);
            p1b = MFMA16(f2, wf[2][2], p1b); p2b = MFMA16(f2, wf[3][2], p2b);
            p1a = MFMA16(f1, wf[2][1], p1a); p2a = MFMA16(f1, wf[3][1], p2a);
            p1b = MFMA16(f3, wf[2][3], p1b); p2b = MFMA16(f3, wf[3][3], p2b);
        }
        float p1v = (row ? p1a[1] : p1a[0]) + (row ? p1b[1] : p1b[0]);
        float p2v = (row ? p2a[1] : p2a[0]) + (row ? p2b[1] : p2b[0]);
        float t1 = c_c ? tp1b : tp1a;
        float t2 = c_c ? tp2b : tp2a;
        float e1p = __builtin_amdgcn_exp2f(p1v + t1), e2p = __builtin_amdgcn_exp2f(p2v + t2);
        float pka = (1.0f - e2p) * __builtin_amdgcn_rcpf((1.0f + e1p) * (1.0f + e2p));
        h = gv * (h - pka) + pka;

        // ---- d-write for step t+1 IMMEDIATELY (critical path) ----
        float xn = upk_x(pkN);
        {
            uint32_t pk = cvtpk(xn - h, xn - h);
            if (owner) *(unsigned short*)pdw = (unsigned short)pk;
        }
        // ---- y partial (off critical path): 16-lane DPP sum -> LDS ybuf ----
        float yv = sum16(xn * h);
        if (owner && cl == 0) ybuf[t & 1][row][w] = yv;
        bar_lgkm();

        // rotate: kip/corr for next iter
        kip_c = upk_k(pkN);
        c_c = ((unsigned int)cN >> row) & 1u;
    }

    // epilogue: y(498) from ybuf, and y(:,499) = 0
    if (w == 0 && l < 2) {
        const float* yb = ybuf[(TT - 1) & 1][l];
        float s = (yb[0] + yb[1]) + (yb[2] + yb[3]) + (yb[4] + yb[5]) + (yb[6] + yb[7]);
        yrow[(size_t)l * SS + (TT - 1)] = fsig(s);
        yrow[(size_t)l * SS + TT] = 0.0f;
    }
}

// ---------------- launch ----------------
extern "C" void kernel_launch(void* const* d_in, const int* in_sizes, int n_in,
                              void* d_out, int out_size, void* d_ws, size_t ws_size,
                              hipStream_t stream) {
    const int* qs    = (const int*)d_in[0];
    const int* cs    = (const int*)d_in[1];
    const int* qds   = (const int*)d_in[2];
    const int* cds   = (const int*)d_in[3];
    const int* corr  = (const int*)d_in[4];
    const float* Eq    = (const float*)d_in[5];
    const float* Ec    = (const float*)d_in[6];
    const float* Eqd   = (const float*)d_in[7];
    const float* Ecd   = (const float*)d_in[8];
    const float* Ecorr = (const float*)d_in[9];
    const float* Wx    = (const float*)d_in[10];
    const float* bx    = (const float*)d_in[11];
    const float* Wsdf1 = (const float*)d_in[12];
    const float* bsdf1 = (const float*)d_in[13];
    const float* Wsdf2 = (const float*)d_in[14];
    const float* bsdf2 = (const float*)d_in[15];
    const float* Wpka1 = (const float*)d_in[16];
    const float* bpka1 = (const float*)d_in[17];
    const float* Wpka2 = (const float*)d_in[18];
    const float* bpka2 = (const float*)d_in[19];
    const float* Wki   = (const float*)d_in[20];
    const float* bki   = (const float*)d_in[21];
    const float* h0    = (const float*)d_in[22];

    char* base;
    if (ws_size >= TOTAL_WS) {
        base = (char*)d_ws;
    } else {
        void* p = nullptr;
        hipGetSymbolAddress(&p, HIP_SYMBOL(g_fb));
        base = (char*)p;
    }

    float2* TQ   = (float2*)(base + OFF_TQ);
    float2* TC   = (float2*)(base + OFF_TC);
    float2* TQD  = (float2*)(base + OFF_TQD);
    float2* TCD  = (float2*)(base + OFF_TCD);
    float* TCOk  = (float*)(base + OFF_TCOK);
    float* Tp1   = (float*)(base + OFF_TP1);
    float* Tp2   = (float*)(base + OFF_TP2);
    float* Wcomb = (float*)(base + OFF_WCOMB);
    float* bkq   = (float*)(base + OFF_BKQ);
    unsigned short* wfrag = (unsigned short*)(base + OFF_WFRAG);
    unsigned char*  cpk   = (unsigned char*)(base + OFF_CPK);
    uint32_t* strm = (uint32_t*)(base + OFF_STRM);

    k_wcomb<<<513, 128, 0, stream>>>(Wx, bx, Wki, Wcomb, bkq);
    k_tables<<<677, 128, 0, stream>>>(Eq, Ec, Eqd, Ecd, Ecorr, Wx, bx,
                                      Wpka1, bpka1, Wpka2, bpka2, Wki, bki,
                                      Wcomb, bkq, TQ, TC, TQD, TCD, TCOk, Tp1, Tp2);
    k_wfrag<<<160, 64, 0, stream>>>(Wsdf1, Wsdf2, Wpka1, Wpka2, Wki, wfrag);
    k_gather<<<SS * 128, 512, 0, stream>>>(qs, cs, qds, cds, corr,
                                           (const float2*)TQ, (const float2*)TC,
                                           (const float2*)TQD, (const float2*)TCD, TCOk,
                                           strm, cpk);
    k_rec<<<NRB, 512, 0, stream>>>(strm, cpk, wfrag, Tp1, Tp2,
                                   bsdf1, bsdf2, h0, (float*)d_out);
}